// Round 1
// baseline (138.215 us; speedup 1.0000x reference)
//
#include <hip/hip_runtime.h>

typedef _Float16 half8 __attribute__((ext_vector_type(8)));
typedef float f32x4 __attribute__((ext_vector_type(4)));
typedef unsigned short u16x4 __attribute__((ext_vector_type(4)));
typedef unsigned short u16x8 __attribute__((ext_vector_type(8)));

#define LOG2E 1.44269504088896340736f

constexpr int NB = 16, LQ = 1024, LK = 1024, DX = 512, DVD = 512;
constexpr int QBLK = 64, KVB = 32, NCH = LK / KVB;
constexpr int VTS = 40;  // Vt row stride in f16 units (80 B)
constexpr int PLS = 40;  // P row stride in f16 units

static __device__ __forceinline__ unsigned short f2h(float f) {
  union { _Float16 h; unsigned short u; } c; c.h = (_Float16)f; return c.u;
}

__global__ void cvt_f32_f16_kv(const float* __restrict__ a, const float* __restrict__ b,
                               unsigned short* __restrict__ oa, unsigned short* __restrict__ ob,
                               int n4each) {
  int i = blockIdx.x * blockDim.x + threadIdx.x;
  int stride = gridDim.x * blockDim.x;
  for (; i < 2 * n4each; i += stride) {
    const float4* s; unsigned short* d; int k;
    if (i < n4each) { s = (const float4*)a; d = oa; k = i; }
    else            { s = (const float4*)b; d = ob; k = i - n4each; }
    float4 v = s[k];
    u16x4 o = { f2h(v.x), f2h(v.y), f2h(v.z), f2h(v.w) };
    *(u16x4*)(d + 4 * (size_t)k) = o;
  }
}

template<bool KV16>
__global__ __launch_bounds__(512, 2) void attn_fused(
    const float* __restrict__ Qf, const float* __restrict__ Kf,
    const float* __restrict__ Vf, const unsigned short* __restrict__ Kh,
    const unsigned short* __restrict__ Vh, float* __restrict__ Out) {
  __shared__ __align__(16) unsigned short Kl[KVB * DX];      // 32 KB, row-swizzled
  __shared__ __align__(16) unsigned short Vt[DVD * VTS];     // 40 KB, transposed V
  __shared__ __align__(16) unsigned short Pl[QBLK * PLS];    // 5 KB
  __shared__ __align__(16) float pmax[2][QBLK];
  __shared__ __align__(16) float psum[2][QBLK];

  const int bid = blockIdx.x;
  // XCD-chunked swizzle: dispatch slot i -> logical (i%8)*32 + i/8, so each
  // XCD hosts 32 consecutive logical blocks = 2 batches (K/V ~L2-resident).
  const int logical = (bid & 7) * 32 + (bid >> 3);
  const int b  = logical >> 4;
  const int qt = logical & 15;
  const int tid = (int)threadIdx.x;
  const int lane = tid & 63;
  const int wave = tid >> 6;
  const int wq = wave >> 1, wd = wave & 1;
  const int q0 = qt * QBLK + wq * 16;   // this wave's 16 q-rows
  const int d0 = wd * 256;              // this wave's Dv half
  const int c15 = lane & 15;
  const int g4  = lane >> 4;
  const int rbase = g4 * 4;             // C-fragment rows = rbase..rbase+3

  // ---- Q fragments: f32 global -> f16 registers, resident all kernel
  half8 qfrag[16];
  {
    const float* qrow = Qf + ((size_t)b * LQ + q0 + c15) * DX + g4 * 8;
#pragma unroll
    for (int ks = 0; ks < 16; ++ks) {
      float4 a0 = *(const float4*)(qrow + ks * 32);
      float4 a1 = *(const float4*)(qrow + ks * 32 + 4);
      half8 f;
      f[0] = (_Float16)a0.x; f[1] = (_Float16)a0.y;
      f[2] = (_Float16)a0.z; f[3] = (_Float16)a0.w;
      f[4] = (_Float16)a1.x; f[5] = (_Float16)a1.y;
      f[6] = (_Float16)a1.z; f[7] = (_Float16)a1.w;
      qfrag[ks] = f;
    }
  }

  f32x4 acc[16];
#pragma unroll
  for (int n = 0; n < 16; ++n) acc[n] = (f32x4){0.f, 0.f, 0.f, 0.f};
  float mr[4], lr[4];
#pragma unroll
  for (int j = 0; j < 4; ++j) { mr[j] = -3.0e38f; lr[j] = 0.f; }

  const int srow = tid >> 4;         // K-staging row 0..31
  const int sx16 = (tid & 15) * 8;
  const int sx32 = (tid & 15) * 4;

  for (int c = 0; c < NCH; ++c) {
    const int kv0 = c * KVB;
    __syncthreads();  // previous iteration's readers done

    // ---- stage K chunk: row-major [32][512] f16, XOR-swizzled (T2)
    if constexpr (KV16) {
      const unsigned short* ks_ = Kh + ((size_t)b * LK + kv0 + srow) * DX;
#pragma unroll
      for (int i = 0; i < 4; ++i) {
        int x = sx16 + i * 128;
        u16x8 v = *(const u16x8*)(ks_ + x);
        *(u16x8*)&Kl[srow * DX + (x ^ ((srow & 7) << 3))] = v;
      }
    } else {
      const float* ks_ = Kf + ((size_t)b * LK + kv0 + srow) * DX;
#pragma unroll
      for (int i = 0; i < 8; ++i) {
        int x = sx32 + i * 64;
        float4 v = *(const float4*)(ks_ + x);
        u16x4 o = { f2h(v.x), f2h(v.y), f2h(v.z), f2h(v.w) };
        *(u16x4*)&Kl[srow * DX + (x ^ ((srow & 7) << 3))] = o;
      }
    }
    // ---- stage V chunk transposed: Vt[dv][kv] (each thread owns one dv)
    {
      unsigned int dw[16];
      if constexpr (KV16) {
        const unsigned short* vs = Vh + ((size_t)b * LK + kv0) * DVD + tid;
#pragma unroll
        for (int kp = 0; kp < 16; ++kp) {
          unsigned int lo = vs[(2 * kp) * DVD];
          unsigned int hi = vs[(2 * kp + 1) * DVD];
          dw[kp] = lo | (hi << 16);
        }
      } else {
        const float* vs = Vf + ((size_t)b * LK + kv0) * DVD + tid;
#pragma unroll
        for (int kp = 0; kp < 16; ++kp) {
          unsigned int lo = f2h(vs[(2 * kp) * DVD]);
          unsigned int hi = f2h(vs[(2 * kp + 1) * DVD]);
          dw[kp] = lo | (hi << 16);
        }
      }
#pragma unroll
      for (int g = 0; g < 4; ++g) {
        uint4 w = { dw[4*g], dw[4*g+1], dw[4*g+2], dw[4*g+3] };
        *(uint4*)&Vt[tid * VTS + g * 8] = w;
      }
    }
    __syncthreads();

    // ---- S = Q·K^T : this wave computes rows q0..+16, chunk cols wd*16..+16
    f32x4 cs = {0.f, 0.f, 0.f, 0.f};
    {
      const int krow = wd * 16 + c15;
      const int kswz = (krow & 7) << 3;
#pragma unroll
      for (int ks = 0; ks < 16; ++ks) {
        int x = g4 * 8 + ks * 32;
        half8 bf = *(const half8*)&Kl[krow * DX + (x ^ kswz)];
        cs = __builtin_amdgcn_mfma_f32_16x16x32_f16(qfrag[ks], bf, cs, 0, 0, 0);
      }
    }

    // ---- partial row-max over this wave's 16 cols (shfl within 16-lane group)
    float pm[4];
#pragma unroll
    for (int j = 0; j < 4; ++j) pm[j] = cs[j];
#pragma unroll
    for (int m = 1; m <= 8; m <<= 1)
#pragma unroll
      for (int j = 0; j < 4; ++j) pm[j] = fmaxf(pm[j], __shfl_xor(pm[j], m, 64));
    if (c15 == 0) *(f32x4*)&pmax[wd][wq * 16 + rbase] = (f32x4){pm[0], pm[1], pm[2], pm[3]};
    __syncthreads();

    // ---- online-softmax update (both wd waves compute identical m/l redundantly)
    f32x4 pm0 = *(const f32x4*)&pmax[0][wq * 16 + rbase];
    f32x4 pm1 = *(const f32x4*)&pmax[1][wq * 16 + rbase];
    float mnew[4], scl[4], p[4];
#pragma unroll
    for (int j = 0; j < 4; ++j) {
      float mt = fmaxf(pm0[j], pm1[j]);
      mnew[j] = fmaxf(mr[j], mt);
      scl[j] = exp2f((mr[j] - mnew[j]) * LOG2E);
      p[j]   = exp2f((cs[j] - mnew[j]) * LOG2E);
    }
    float ps[4];
#pragma unroll
    for (int j = 0; j < 4; ++j) ps[j] = p[j];
#pragma unroll
    for (int m = 1; m <= 8; m <<= 1)
#pragma unroll
      for (int j = 0; j < 4; ++j) ps[j] += __shfl_xor(ps[j], m, 64);
    if (c15 == 0) *(f32x4*)&psum[wd][wq * 16 + rbase] = (f32x4){ps[0], ps[1], ps[2], ps[3]};
#pragma unroll
    for (int j = 0; j < 4; ++j)
      Pl[(wq * 16 + rbase + j) * PLS + wd * 16 + c15] = f2h(p[j]);
#pragma unroll
    for (int n = 0; n < 16; ++n)
#pragma unroll
      for (int j = 0; j < 4; ++j) acc[n][j] *= scl[j];
#pragma unroll
    for (int j = 0; j < 4; ++j) mr[j] = mnew[j];
    __syncthreads();

    // ---- l update + PV
    f32x4 ps0 = *(const f32x4*)&psum[0][wq * 16 + rbase];
    f32x4 ps1 = *(const f32x4*)&psum[1][wq * 16 + rbase];
#pragma unroll
    for (int j = 0; j < 4; ++j) lr[j] = lr[j] * scl[j] + ps0[j] + ps1[j];

    half8 pa = *(const half8*)&Pl[(wq * 16 + c15) * PLS + g4 * 8];
#pragma unroll
    for (int n = 0; n < 16; ++n) {
      half8 bv = *(const half8*)&Vt[(d0 + n * 16 + c15) * VTS + g4 * 8];
      acc[n] = __builtin_amdgcn_mfma_f32_16x16x32_f16(pa, bv, acc[n], 0, 0, 0);
    }
  }

  // ---- epilogue: O /= l, store f32
  float inv[4];
#pragma unroll
  for (int j = 0; j < 4; ++j) inv[j] = 1.0f / lr[j];
  float* ob = Out + ((size_t)b * LQ + q0 + rbase) * DVD + d0 + c15;
#pragma unroll
  for (int n = 0; n < 16; ++n)
#pragma unroll
    for (int j = 0; j < 4; ++j)
      ob[(size_t)j * DVD + n * 16] = acc[n][j] * inv[j];
}

extern "C" void kernel_launch(void* const* d_in, const int* in_sizes, int n_in,
                              void* d_out, int out_size, void* d_ws, size_t ws_size,
                              hipStream_t stream) {
  const float* Qf = (const float*)d_in[0];
  const float* Kf = (const float*)d_in[1];
  const float* Vf = (const float*)d_in[2];
  float* Out = (float*)d_out;

  const size_t nKV = (size_t)NB * LK * DX;            // 8,388,608 elements
  const size_t need = 2 * nKV * sizeof(unsigned short); // 33.5 MB

  if (ws_size >= need) {
    unsigned short* Kh = (unsigned short*)d_ws;
    unsigned short* Vh = Kh + nKV;
    cvt_f32_f16_kv<<<2048, 256, 0, stream>>>(Kf, Vf, Kh, Vh, (int)(nKV / 4));
    attn_fused<true><<<NB * (LQ / QBLK), 512, 0, stream>>>(Qf, Kf, Vf, Kh, Vh, Out);
  } else {
    attn_fused<false><<<NB * (LQ / QBLK), 512, 0, stream>>>(Qf, Kf, Vf, nullptr, nullptr, Out);
  }
}

// Round 2
// 136.294 us; speedup vs baseline: 1.0141x; 1.0141x over previous
//
#include <hip/hip_runtime.h>

typedef _Float16 half8 __attribute__((ext_vector_type(8)));
typedef float f32x4 __attribute__((ext_vector_type(4)));
typedef unsigned short u16x8 __attribute__((ext_vector_type(8)));

#define LOG2E 1.44269504088896340736f

constexpr int NB = 16, LQ = 1024, LK = 1024, DX = 512, DVD = 512;
constexpr int QBLK = 64, KVB = 32, NCH = LK / KVB;
constexpr int KTILE = KVB * DX;   // 16384 u16 per K buffer
constexpr int VTILE = KVB * DVD;  // 16384 u16 per V buffer

static __device__ __forceinline__ unsigned short f2h(float f) {
  union { _Float16 h; unsigned short u; } c; c.h = (_Float16)f; return c.u;
}

static __device__ __forceinline__ void gload16(const unsigned short* g, unsigned short* l) {
  __builtin_amdgcn_global_load_lds(
      (const __attribute__((address_space(1))) unsigned int*)g,
      (__attribute__((address_space(3))) unsigned int*)l, 16, 0, 0);
}

static __device__ __forceinline__ void bar_lgkm() {
  asm volatile("s_waitcnt lgkmcnt(0)" ::: "memory");
  __builtin_amdgcn_s_barrier();
  __builtin_amdgcn_sched_barrier(0);
}

// ---- prep 1: K f32 -> f16, same [b][k][x] layout
__global__ void cvt_k(const float* __restrict__ K, unsigned short* __restrict__ Kh) {
  size_t i = ((size_t)blockIdx.x * 256 + threadIdx.x) * 8;
  float4 a = *(const float4*)(K + i);
  float4 b = *(const float4*)(K + i + 4);
  u16x8 o = { f2h(a.x), f2h(a.y), f2h(a.z), f2h(a.w),
              f2h(b.x), f2h(b.y), f2h(b.z), f2h(b.w) };
  *(u16x8*)(Kh + i) = o;
}

// ---- prep 2: V [b][k][d] f32 -> Vt [b][d][k] f16 (64x64 LDS tiles)
__global__ void cvt_transpose_v(const float* __restrict__ V, unsigned short* __restrict__ Vt) {
  __shared__ float tile[64][65];
  const int bidx = blockIdx.x;          // 16 b * 16 ktiles * 8 dtiles
  const int b  = bidx >> 7;
  const int kt = (bidx >> 3) & 15;
  const int dt = bidx & 7;
  const int t = threadIdx.x;            // 256
  const int r  = t >> 4;                // 0..15
  const int c4 = (t & 15) * 4;
  const float* src = V + ((size_t)b * LK + kt * 64) * DVD + dt * 64;
#pragma unroll
  for (int i = 0; i < 4; ++i) {
    float4 v = *(const float4*)(src + (size_t)(r + i * 16) * DVD + c4);
    tile[r + i * 16][c4 + 0] = v.x; tile[r + i * 16][c4 + 1] = v.y;
    tile[r + i * 16][c4 + 2] = v.z; tile[r + i * 16][c4 + 3] = v.w;
  }
  __syncthreads();
  const int dr  = t >> 2;               // 0..63
  const int seg = t & 3;                // 16 k each
  unsigned short ob[16];
#pragma unroll
  for (int i = 0; i < 16; ++i) ob[i] = f2h(tile[seg * 16 + i][dr]);
  unsigned short* dst = Vt + ((size_t)b * DVD + dt * 64 + dr) * LK + kt * 64 + seg * 16;
  *(u16x8*)dst = *(const u16x8*)&ob[0];
  *(u16x8*)(dst + 8) = *(const u16x8*)&ob[8];
}

// ---- main fused attention
__global__ __launch_bounds__(512, 2) void attn_fused2(
    const float* __restrict__ Qf, const unsigned short* __restrict__ Kh,
    const unsigned short* __restrict__ Vt, float* __restrict__ Out) {
  // K layout: [buf][part=x/8 (64)][kv (32)][8]   part stride 256 u16
  // V layout: [buf][pv=kvloc/8 (4)][d (512)][8]  pv stride 4096 u16
  // P layout: [pp=kvloc/8 (4)][q (64)][8]        pp stride 512 u16
  __shared__ __align__(16) unsigned short Kl[2][KTILE];
  __shared__ __align__(16) unsigned short Vl[2][VTILE];
  __shared__ __align__(16) unsigned short Pl[4 * QBLK * 8];
  __shared__ __align__(16) float pmax[2][QBLK];

  const int bid = blockIdx.x;
  const int logical = (bid & 7) * 32 + (bid >> 3);  // XCD-chunked: 2 batches/XCD
  const int b  = logical >> 4;
  const int qt = logical & 15;
  const int tid = (int)threadIdx.x;
  const int lane = tid & 63;
  const int wave = tid >> 6;            // 0..7
  const int wq = wave >> 1, wd = wave & 1;
  const int q0 = qt * QBLK + wq * 16;
  const int d0 = wd * 256;
  const int c15 = lane & 15;
  const int g4  = lane >> 4;
  const int rbase = g4 * 4;

  // ---- Q fragments: f32 global -> f16 registers
  half8 qfrag[16];
  {
    const float* qrow = Qf + ((size_t)b * LQ + q0 + c15) * DX + g4 * 8;
#pragma unroll
    for (int ks = 0; ks < 16; ++ks) {
      float4 a0 = *(const float4*)(qrow + ks * 32);
      float4 a1 = *(const float4*)(qrow + ks * 32 + 4);
      half8 f;
      f[0] = (_Float16)a0.x; f[1] = (_Float16)a0.y;
      f[2] = (_Float16)a0.z; f[3] = (_Float16)a0.w;
      f[4] = (_Float16)a1.x; f[5] = (_Float16)a1.y;
      f[6] = (_Float16)a1.z; f[7] = (_Float16)a1.w;
      qfrag[ks] = f;
    }
  }

  f32x4 acc[16];
#pragma unroll
  for (int n = 0; n < 16; ++n) acc[n] = (f32x4){0.f, 0.f, 0.f, 0.f};
  float mr[4], lr[4];
#pragma unroll
  for (int j = 0; j < 4; ++j) { mr[j] = -3.0e38f; lr[j] = 0.f; }

  // ---- staging descriptors (4 K-insts + 4 V-insts per wave per chunk)
  const unsigned short* ksrc0[4];
  const unsigned short* vsrc0[4];
  int kdoff[4], vdoff[4];
#pragma unroll
  for (int ii = 0; ii < 4; ++ii) {
    const int i = wave * 4 + ii;        // 0..31
    kdoff[ii] = i * 512;
    ksrc0[ii] = Kh + (size_t)b * LK * DX + (size_t)(lane & 31) * DX
                + (2 * i + (lane >> 5)) * 8;
    const int pv = i >> 3, dblk = (i & 7) * 64;
    vdoff[ii] = pv * 4096 + dblk * 8;
    vsrc0[ii] = Vt + (size_t)b * DVD * LK + (size_t)(dblk + lane) * LK + pv * 8;
  }

  // ---- prologue: stage chunk 0 into buffer 0
#pragma unroll
  for (int ii = 0; ii < 4; ++ii) gload16(ksrc0[ii], &Kl[0][kdoff[ii]]);
#pragma unroll
  for (int ii = 0; ii < 4; ++ii) gload16(vsrc0[ii], &Vl[0][vdoff[ii]]);
  __syncthreads();

  for (int c = 0; c < NCH; ++c) {
    const int cur = c & 1;

    // ---- issue next chunk's staging into the other buffer (stays in flight
    //      across the raw barriers below; drained at loop-end __syncthreads)
    if (c + 1 < NCH) {
      const size_t kadv = (size_t)(c + 1) * KVB * DX;
      const int    vadv = (c + 1) * KVB;
#pragma unroll
      for (int ii = 0; ii < 4; ++ii) gload16(ksrc0[ii] + kadv, &Kl[cur ^ 1][kdoff[ii]]);
#pragma unroll
      for (int ii = 0; ii < 4; ++ii) gload16(vsrc0[ii] + vadv, &Vl[cur ^ 1][vdoff[ii]]);
    }

    // ---- QK^T: wave computes S[16q][16kv], kv-half selected by wd
    f32x4 cs = {0.f, 0.f, 0.f, 0.f};
    {
      const unsigned short* kb = &Kl[cur][(wd * 16 + c15) * 8 + g4 * 256];
#pragma unroll
      for (int ks = 0; ks < 16; ++ks) {
        half8 bf = *(const half8*)(kb + ks * 1024);   // part = ks*4+g4
        cs = __builtin_amdgcn_mfma_f32_16x16x32_f16(qfrag[ks], bf, cs, 0, 0, 0);
      }
    }

    // ---- partial row-max over this wave's 16 kv (shfl within 16-lane group)
    float pm[4];
#pragma unroll
    for (int j = 0; j < 4; ++j) pm[j] = cs[j];
#pragma unroll
    for (int m = 1; m <= 8; m <<= 1)
#pragma unroll
      for (int j = 0; j < 4; ++j) pm[j] = fmaxf(pm[j], __shfl_xor(pm[j], m, 64));
    if (c15 == 0) *(f32x4*)&pmax[wd][wq * 16 + rbase] = (f32x4){pm[0], pm[1], pm[2], pm[3]};

    bar_lgkm();  // barrier A: pmax visible; DMA stays in flight

    f32x4 pm0 = *(const f32x4*)&pmax[0][wq * 16 + rbase];
    f32x4 pm1 = *(const f32x4*)&pmax[1][wq * 16 + rbase];
    float scl[4];
#pragma unroll
    for (int j = 0; j < 4; ++j) {
      float mnew = fmaxf(mr[j], fmaxf(pm0[j], pm1[j]));
      scl[j] = exp2f((mr[j] - mnew) * LOG2E);
      float p = exp2f((cs[j] - mnew) * LOG2E);
      mr[j] = mnew;
      Pl[(wd * 2 + (c15 >> 3)) * 512 + (wq * 16 + rbase + j) * 8 + (c15 & 7)] = f2h(p);
    }
#pragma unroll
    for (int n = 0; n < 16; ++n)
#pragma unroll
      for (int j = 0; j < 4; ++j) acc[n][j] *= scl[j];

    bar_lgkm();  // barrier B: P visible; DMA still in flight

    // ---- P A-fragment + in-register row-sum (replaces psum exchange)
    half8 pa = *(const half8*)&Pl[g4 * 512 + (wq * 16 + c15) * 8];
    float s = 0.f;
#pragma unroll
    for (int e = 0; e < 8; ++e) s += (float)pa[e];
    s += __shfl_xor(s, 16, 64);
    s += __shfl_xor(s, 32, 64);
#pragma unroll
    for (int j = 0; j < 4; ++j) {
      float lsum = __shfl(s, (lane & 48) | (rbase + j), 64);
      lr[j] = lr[j] * scl[j] + lsum;
    }

    // ---- PV: acc[n] += P * V[:, d0+n*16+c15]
    {
      const unsigned short* vb = &Vl[cur][g4 * 4096 + (d0 + c15) * 8];
#pragma unroll
      for (int n = 0; n < 16; ++n) {
        half8 bv = *(const half8*)(vb + n * 128);
        acc[n] = __builtin_amdgcn_mfma_f32_16x16x32_f16(pa, bv, acc[n], 0, 0, 0);
      }
    }

    __syncthreads();  // barrier C: drains DMA (vmcnt 0) + all LDS readers
  }

  // ---- epilogue: O /= l
  float inv[4];
#pragma unroll
  for (int j = 0; j < 4; ++j) inv[j] = 1.0f / lr[j];
  float* ob = Out + ((size_t)b * LQ + q0 + rbase) * DVD + d0 + c15;
#pragma unroll
  for (int n = 0; n < 16; ++n)
#pragma unroll
    for (int j = 0; j < 4; ++j)
      ob[(size_t)j * DVD + n * 16] = acc[n][j] * inv[j];
}

extern "C" void kernel_launch(void* const* d_in, const int* in_sizes, int n_in,
                              void* d_out, int out_size, void* d_ws, size_t ws_size,
                              hipStream_t stream) {
  const float* Qf = (const float*)d_in[0];
  const float* Kf = (const float*)d_in[1];
  const float* Vf = (const float*)d_in[2];
  float* Out = (float*)d_out;

  unsigned short* Kh = (unsigned short*)d_ws;
  unsigned short* Vt = Kh + (size_t)NB * LK * DX;   // 16.7 MB each, 33.5 MB total

  cvt_k<<<4096, 256, 0, stream>>>(Kf, Kh);
  cvt_transpose_v<<<NB * 16 * 8, 256, 0, stream>>>(Vf, Vt);
  attn_fused2<<<NB * (LQ / QBLK), 512, 0, stream>>>(Qf, Kh, Vt, Out);
}